// Round 5
// baseline (1936.166 us; speedup 1.0000x reference)
//
#include <hip/hip_runtime.h>
#include <math.h>

#define NB   64
#define SS   96
#define EE   300
#define DD   512
#define HH   256
#define SELD 128
#define CK   1280   // 5*H
#define MLPD 1024
#define NCLS 3
#define RB   97     // state rows per batch: 96 initial + 1 spare (freed-row recycling)

// ---------------- transpose W_sel1 [e][k] -> [e4][k] float4 (4 consecutive e rows at col k) ------
__global__ void k_trans_sel(const float* __restrict__ Ws, float* __restrict__ Ws4) {
    int e4 = blockIdx.x;            // 0..127
    int k = threadIdx.x;            // 0..127
    float4 v;
    v.x = Ws[(4 * e4 + 0) * SELD + k];
    v.y = Ws[(4 * e4 + 1) * SELD + k];
    v.z = Ws[(4 * e4 + 2) * SELD + k];
    v.w = Ws[(4 * e4 + 3) * SELD + k];
    ((float4*)Ws4)[e4 * SELD + k] = v;
}

// ---------------- init parity-0 bookkeeping ------------------------------------------------------
__global__ void k_init(int* __restrict__ acts, int* __restrict__ rec) {
    int b = blockIdx.x, tid = threadIdx.x;
    acts[b * SS + tid] = tid;                     // parity-0
    if (tid == 0) {
        int* r = rec + b * 4;                     // parity-0
        r[0] = 0; r[1] = 0; r[2] = 0; r[3] = SS;  // pidx, pv0, pv1, freerow
    }
}

// ---------------- encode: states[b][s][:] = emb[sent[b][s]] @ W_enc + b_enc ----------------------
// v2: x via uniform global float4 loads (L1-served broadcast), 2 output cols/thread.
__global__ __launch_bounds__(256) void k_encode(const int* __restrict__ sent,
                                                const float* __restrict__ emb,
                                                const float* __restrict__ Wenc,
                                                const float* __restrict__ benc,
                                                float* __restrict__ state) {
    int b = blockIdx.x / 3, tile = blockIdx.x % 3, s0 = tile * 32;
    __shared__ int toff[32];
    int tid = threadIdx.x;
    if (tid < 32) toff[tid] = sent[b * SS + s0 + tid] * 75;   // row offset in float4 units
    __syncthreads();
    int off[32];
#pragma unroll
    for (int s = 0; s < 32; s++) off[s] = toff[s];
    const float4* e4p = (const float4*)emb;
    float acc0[32], acc1[32];
    float bv0 = benc[tid], bv1 = benc[256 + tid];
#pragma unroll
    for (int s = 0; s < 32; s++) { acc0[s] = bv0; acc1[s] = bv1; }
    for (int e4 = 0; e4 < 75; e4++) {
        float w00 = Wenc[(4 * e4 + 0) * DD + tid];
        float w01 = Wenc[(4 * e4 + 1) * DD + tid];
        float w02 = Wenc[(4 * e4 + 2) * DD + tid];
        float w03 = Wenc[(4 * e4 + 3) * DD + tid];
        float w10 = Wenc[(4 * e4 + 0) * DD + 256 + tid];
        float w11 = Wenc[(4 * e4 + 1) * DD + 256 + tid];
        float w12 = Wenc[(4 * e4 + 2) * DD + 256 + tid];
        float w13 = Wenc[(4 * e4 + 3) * DD + 256 + tid];
#pragma unroll
        for (int sq = 0; sq < 4; sq++) {
            float4 xv[8];
#pragma unroll
            for (int s = 0; s < 8; s++) xv[s] = e4p[off[sq * 8 + s] + e4];
#pragma unroll
            for (int s = 0; s < 8; s++) {
                int si = sq * 8 + s;
                acc0[si] += xv[s].x * w00 + xv[s].y * w01 + xv[s].z * w02 + xv[s].w * w03;
                acc1[si] += xv[s].x * w10 + xv[s].y * w11 + xv[s].z * w12 + xv[s].w * w13;
            }
        }
    }
    for (int s = 0; s < 32; s++) {
        state[((size_t)b * RB + s0 + s) * DD + tid] = acc0[s];
        state[((size_t)b * RB + s0 + s) * DD + 256 + tid] = acc1[s];
    }
}

// ---------------- initial logits for all 95 pairs per batch (parity-0) ---------------------------
__global__ __launch_bounds__(128) void k_logits0(const float* __restrict__ state,
                                                 const float* __restrict__ Ws4,
                                                 const float* __restrict__ bs1,
                                                 const float* __restrict__ Ws2,
                                                 const float* __restrict__ bs2,
                                                 float* __restrict__ logits) {
    int b = blockIdx.x / 5, tile = blockIdx.x % 5, p0 = tile * 19;
    __shared__ __align__(16) float hl[20 * 256];
    __shared__ float part[2][19];
    int tid = threadIdx.x;
    for (int i = tid; i < 20 * 256; i += 128) {
        int r = i >> 8, c = i & 255;
        hl[i] = state[((size_t)b * RB + p0 + r) * DD + HH + c];
    }
    __syncthreads();
    int k = tid;
    float acc[19];
#pragma unroll
    for (int p = 0; p < 19; p++) acc[p] = 0.f;
    const float4* W4 = (const float4*)Ws4;
    const float4* h4 = (const float4*)hl;
    for (int e4 = 0; e4 < 128; e4++) {
        float4 w = W4[e4 * SELD + k];
#pragma unroll
        for (int p = 0; p < 19; p++) {
            float4 x = h4[p * 64 + e4];
            acc[p] += x.x * w.x + x.y * w.y + x.z * w.z + x.w * w.w;
        }
    }
    float b1 = bs1[k], w2 = Ws2[k];
    int wid = tid >> 6, lane = tid & 63;
#pragma unroll
    for (int p = 0; p < 19; p++) {
        float y = tanhf(acc[p] + b1) * w2;
        for (int off = 32; off >= 1; off >>= 1) y += __shfl_down(y, off);
        if (lane == 0) part[wid][p] = y;
    }
    __syncthreads();
    if (tid < 19) logits[b * SS + p0 + tid] = part[0][tid] + part[1][tid] + bs2[0];
}

// ---------------- fused step kernel v2: 256 blocks = 16 batch-groups x 16 unit-tiles -------------
// 320 threads. Matvec: thread = (b:4, ks:8, c8:10) -> 8 cols x 64 K-elems, weights as float4
// pairs straight from W_comp (L1-amortized), x as uniform global float4 from state rows.
__global__ __launch_bounds__(320) void k_step(const float* __restrict__ Wc,
                                              const float* __restrict__ bcomp,
                                              const float* __restrict__ Ws4,
                                              const float* __restrict__ bs1,
                                              const float* __restrict__ Ws2,
                                              const float* __restrict__ bs2,
                                              float* __restrict__ logits,
                                              int* __restrict__ acts,
                                              int* __restrict__ rec,
                                              int* __restrict__ nlUsed,
                                              float* __restrict__ Psel,
                                              float* __restrict__ state, int t) {
    int bid = blockIdx.x, bg = bid & 15, ut = bid >> 4;
    int tid = threadIdx.x, w = tid >> 6, lane = tid & 63;
    int n = SS - t, p = t & 1, np = p ^ 1;

    __shared__ float lgl[4][SS];                 // patched logits copies
    __shared__ int recl[4][8];                   // idx,l,r,nl,lm1,r2,v0,v1
    __shared__ float L01[4][2];
    __shared__ float cl[4][16], cr[4][16];
    __shared__ float lm1s[4][16], r2s[4][16];
    __shared__ float hn[4][16];
    __shared__ float spart[4][80][9];            // padded (9) to break bank conflicts
    __shared__ float a_l[4][5][16];
    __shared__ float ppex[4][2][2][SELD];        // [b][pair][whichW][k]

    // ---- phase 1: refresh values for the 2 holes (from prev step's Psel partials) ----
    if (t > 0 && tid < 256) {
        int b = bg * 4 + w;
        const int* rp = rec + ((size_t)p * NB + b) * 4;
        int pv0 = rp[1], pv1 = rp[2];
        if (pv0 | pv1) {
            float sA0 = bs1[lane], sA1 = bs1[lane + 64];
            float sB0 = sA0, sB1 = sA1;
            const float* Pb = Psel + ((size_t)(p * NB + b) * 16) * 256;
#pragma unroll
            for (int u2 = 0; u2 < 16; u2++) {
                const float* Pu = Pb + u2 * 256;
                sA0 += Pu[lane]; sA1 += Pu[lane + 64];
                sB0 += Pu[128 + lane]; sB1 += Pu[128 + lane + 64];
            }
            float yA = tanhf(sA0) * Ws2[lane] + tanhf(sA1) * Ws2[lane + 64];
            float yB = tanhf(sB0) * Ws2[lane] + tanhf(sB1) * Ws2[lane + 64];
#pragma unroll
            for (int off = 1; off < 64; off <<= 1) {
                yA += __shfl_xor(yA, off);
                yB += __shfl_xor(yB, off);
            }
            if (lane == 0) { L01[w][0] = yA + bs2[0]; L01[w][1] = yB + bs2[0]; }
        }
    }
    __syncthreads();

    // ---- phase 2: patch + argmax (numpy first-max) ----
    if (tid < 256) {
        int b = bg * 4 + w;
        const float* lgp = logits + ((size_t)p * NB + b) * SS;
        const int* rp = rec + ((size_t)p * NB + b) * 4;
        int pidx = rp[0], pv0 = rp[1], pv1 = rp[2], freerow = rp[3];
        int j0 = lane, j1 = lane + 64;
        float x0v = (j0 <= n - 2) ? lgp[j0] : -3.0e38f;
        float x1v = (j1 <= n - 2) ? lgp[j1] : -3.0e38f;
        if (t > 0) {
            if (pv0) { if (j0 == pidx - 1) x0v = L01[w][0]; if (j1 == pidx - 1) x1v = L01[w][0]; }
            if (pv1) { if (j0 == pidx)     x0v = L01[w][1]; if (j1 == pidx)     x1v = L01[w][1]; }
        }
        if (j0 <= n - 2) lgl[w][j0] = x0v;
        if (j1 <= n - 2) lgl[w][j1] = x1v;
        float v = x0v; int i = j0;
        if (x1v > v) { v = x1v; i = j1; }
#pragma unroll
        for (int off = 1; off < 64; off <<= 1) {
            float ov = __shfl_xor(v, off);
            int oi = __shfl_xor(i, off);
            if (ov > v || (ov == v && oi < i)) { v = ov; i = oi; }
        }
        if (lane == 0) {
            const int* acp = acts + ((size_t)p * NB + b) * SS;
            int idx = i;
            int l = acp[idx], r = acp[idx + 1];
            int v0 = (idx >= 1), v1 = (idx <= n - 3);
            recl[w][0] = idx; recl[w][1] = l; recl[w][2] = r; recl[w][3] = freerow;
            recl[w][4] = v0 ? acp[idx - 1] : 0;
            recl[w][5] = v1 ? acp[idx + 2] : 0;
            recl[w][6] = v0; recl[w][7] = v1;
        }
    }
    __syncthreads();

    // ---- stage small slices (c of l/r; h-slices of lm1/r2) ----
    if (tid < 256) {
        int which = tid >> 6, b2 = (tid >> 4) & 3, u = tid & 15;
        const float* sb = state + (size_t)(bg * 4 + b2) * RB * DD;
        if (which == 0)      cl[b2][u]   = sb[(size_t)recl[b2][1] * DD + ut * 16 + u];
        else if (which == 1) cr[b2][u]   = sb[(size_t)recl[b2][2] * DD + ut * 16 + u];
        else if (which == 2) lm1s[b2][u] = sb[(size_t)recl[b2][4] * DD + HH + ut * 16 + u];
        else                 r2s[b2][u]  = sb[(size_t)recl[b2][5] * DD + HH + ut * 16 + u];
    }

    // ---- phase 7 (ut==0): shift bookkeeping into parity t+1 (overlaps matvec) ----
    if (ut == 0 && tid < 256) {
        int b = bg * 4 + w;
        int idx = recl[w][0], l = recl[w][1], nl = recl[w][3];
        int v0 = recl[w][6], v1 = recl[w][7];
        const int* acp = acts + ((size_t)p * NB + b) * SS;
        int* acn = acts + ((size_t)np * NB + b) * SS;
        float* lgn = logits + ((size_t)np * NB + b) * SS;
        for (int j = lane; j <= n - 2; j += 64)
            acn[j] = (j < idx) ? acp[j] : ((j == idx) ? nl : acp[j + 1]);
        for (int j = lane; j <= n - 3; j += 64)
            if (j != idx - 1 && j != idx)
                lgn[j] = (j < idx - 1) ? lgl[w][j] : lgl[w][j + 1];
        if (lane == 0) {
            int* rn = rec + ((size_t)np * NB + b) * 4;
            rn[0] = idx; rn[1] = v0; rn[2] = v1; rn[3] = l;
            nlUsed[b] = nl;
        }
    }

    // ---- phase 4: compose matvec ----
    {
        int b = tid / 80, rem = tid % 80, ks = rem / 10, c8g = rem % 10;
        int i0 = c8g * 8, g = i0 >> 4, u0 = i0 & 15;
        int col0 = g * 256 + ut * 16 + u0;
        int xrow = (ks < 4) ? recl[b][1] : recl[b][2];
        const float4* xb = (const float4*)(state + ((size_t)(bg * 4 + b) * RB + xrow) * DD + HH)
                           + (ks & 3) * 16;
        const float* wb = Wc + (size_t)(ks * 64) * CK + col0;
        float acc[8];
#pragma unroll
        for (int j = 0; j < 8; j++) acc[j] = 0.f;
#pragma unroll 4
        for (int i = 0; i < 16; i++) {
            float4 xv = xb[i];
#pragma unroll
            for (int j = 0; j < 4; j++) {
                const float* wr = wb + (size_t)(i * 4 + j) * CK;
                float4 w0 = *(const float4*)(wr);
                float4 w1 = *(const float4*)(wr + 4);
                float xs = (j == 0) ? xv.x : (j == 1) ? xv.y : (j == 2) ? xv.z : xv.w;
                acc[0] += xs * w0.x; acc[1] += xs * w0.y; acc[2] += xs * w0.z; acc[3] += xs * w0.w;
                acc[4] += xs * w1.x; acc[5] += xs * w1.y; acc[6] += xs * w1.z; acc[7] += xs * w1.w;
            }
        }
#pragma unroll
        for (int j = 0; j < 8; j++) spart[b][i0 + j][ks] = acc[j];
    }
    __syncthreads();

    // ---- reduce K-partials + bias ----
    {
        int b = tid / 80, i = tid % 80;
        const float* sp = spart[b][i];
        float a = sp[0] + sp[1] + sp[2] + sp[3] + sp[4] + sp[5] + sp[6] + sp[7];
        int g = i >> 4, u = i & 15;
        a_l[b][g][u] = a + bcomp[g * 256 + ut * 16 + u];
    }
    __syncthreads();

    // ---- phase 5: gates + write composed c,h into fresh row ----
    if (tid < 64) {
        int b = tid >> 4, u = tid & 15;
        float ai = a_l[b][0][u], afl = a_l[b][1][u], afr = a_l[b][2][u];
        float ao = a_l[b][3][u], agc = a_l[b][4][u];
        float si  = 1.f / (1.f + expf(-ai));
        float sfl = 1.f / (1.f + expf(-afl));
        float sfr = 1.f / (1.f + expf(-afr));
        float so  = 1.f / (1.f + expf(-ao));
        float cv = sfl * cl[b][u] + sfr * cr[b][u] + si * tanhf(agc);
        float hv = so * tanhf(cv);
        float* sb = state + (size_t)(bg * 4 + b) * RB * DD;
        int nl = recl[b][3];
        sb[(size_t)nl * DD + ut * 16 + u] = cv;
        sb[(size_t)nl * DD + HH + ut * 16 + u] = hv;
        hn[b][u] = hv;
    }
    __syncthreads();

    // ---- phase 6: sel partials for next step (own 32 x-dims) ----
    if (tid < 256) {
        int k = tid & 127, whichW = tid >> 7;
        int e4base = (whichW ? 64 : 0) + ut * 4;
        const float4* W4 = (const float4*)Ws4;
        float P0[4] = {0.f, 0.f, 0.f, 0.f}, P1[4] = {0.f, 0.f, 0.f, 0.f};
#pragma unroll
        for (int j = 0; j < 4; j++) {
            float4 wv = W4[(size_t)(e4base + j) * SELD + k];
#pragma unroll
            for (int b4 = 0; b4 < 4; b4++) {
                const float* xa0 = whichW ? hn[b4] : lm1s[b4];
                const float* xa1 = whichW ? r2s[b4] : hn[b4];
                P0[b4] += wv.x * xa0[4 * j] + wv.y * xa0[4 * j + 1]
                        + wv.z * xa0[4 * j + 2] + wv.w * xa0[4 * j + 3];
                P1[b4] += wv.x * xa1[4 * j] + wv.y * xa1[4 * j + 1]
                        + wv.z * xa1[4 * j + 2] + wv.w * xa1[4 * j + 3];
            }
        }
#pragma unroll
        for (int b4 = 0; b4 < 4; b4++) {
            ppex[b4][0][whichW][k] = P0[b4];
            ppex[b4][1][whichW][k] = P1[b4];
        }
    }
    __syncthreads();
    if (tid < 256) {
        int k = tid & 127, pr = tid >> 7;
#pragma unroll
        for (int b4 = 0; b4 < 4; b4++) {
            int b = bg * 4 + b4;
            Psel[((size_t)(np * NB + b) * 16 + ut) * 256 + pr * 128 + k] =
                ppex[b4][pr][0][k] + ppex[b4][pr][1][k];
        }
    }
}

// ---------------- MLP head, column-parallel ------------------------------------------------------
__global__ __launch_bounds__(256) void k_mlp1(const float* __restrict__ state,
                                              const int* __restrict__ nlUsed,
                                              const float* __restrict__ Wm1,
                                              const float* __restrict__ bm1,
                                              float* __restrict__ x1g) {
    int b = blockIdx.x >> 2, q = blockIdx.x & 3, tid = threadIdx.x;
    int col = q * 256 + tid;
    __shared__ float x0[HH];
    int root = nlUsed[b];
    x0[tid] = state[((size_t)b * RB + root) * DD + HH + tid];
    __syncthreads();
    float acc = bm1[col];
    for (int e = 0; e < HH; e++) acc += x0[e] * Wm1[(size_t)e * MLPD + col];
    x1g[(size_t)b * MLPD + col] = fmaxf(acc, 0.f);
}

__global__ __launch_bounds__(128) void k_mlp2(const float* __restrict__ x1g,
                                              const float* __restrict__ Wm2,
                                              const float* __restrict__ bm2,
                                              float* __restrict__ x2g) {
    int b = blockIdx.x >> 3, q = blockIdx.x & 7, tid = threadIdx.x;
    int col = q * 128 + tid;
    __shared__ __align__(16) float x1[MLPD];
    for (int i = tid; i < 256; i += 128)
        ((float4*)x1)[i] = ((const float4*)(x1g + (size_t)b * MLPD))[i];
    __syncthreads();
    float acc = bm2[col];
    for (int e = 0; e < MLPD; e++) acc += x1[e] * Wm2[(size_t)e * MLPD + col];
    x2g[(size_t)b * MLPD + col] = fmaxf(acc, 0.f);
}

__global__ __launch_bounds__(256) void k_mlp3(const float* __restrict__ x2g,
                                              const float* __restrict__ Wout,
                                              const float* __restrict__ bout,
                                              float* __restrict__ out) {
    int b = blockIdx.x, tid = threadIdx.x;
    __shared__ __align__(16) float x2[MLPD];
    __shared__ float red3[3][256];
    ((float4*)x2)[tid] = ((const float4*)(x2g + (size_t)b * MLPD))[tid];
    __syncthreads();
    float p0 = 0.f, p1 = 0.f, p2 = 0.f;
    for (int e = tid; e < MLPD; e += 256) {
        float x = x2[e];
        p0 += x * Wout[e * NCLS + 0];
        p1 += x * Wout[e * NCLS + 1];
        p2 += x * Wout[e * NCLS + 2];
    }
    red3[0][tid] = p0; red3[1][tid] = p1; red3[2][tid] = p2;
    __syncthreads();
    for (int sdd = 128; sdd >= 1; sdd >>= 1) {
        if (tid < sdd) {
            red3[0][tid] += red3[0][tid + sdd];
            red3[1][tid] += red3[1][tid + sdd];
            red3[2][tid] += red3[2][tid + sdd];
        }
        __syncthreads();
    }
    if (tid < NCLS) out[b * NCLS + tid] = red3[tid][0] + bout[tid];
}

extern "C" void kernel_launch(void* const* d_in, const int* in_sizes, int n_in,
                              void* d_out, int out_size, void* d_ws, size_t ws_size,
                              hipStream_t stream) {
    const int*   sent  = (const int*)d_in[0];
    // d_in[1] = transitions: unused by the reference
    const float* emb   = (const float*)d_in[2];
    const float* Wenc  = (const float*)d_in[3];
    const float* benc  = (const float*)d_in[4];
    const float* Wcomp = (const float*)d_in[5];
    const float* bcomp = (const float*)d_in[6];
    const float* Wsel1 = (const float*)d_in[7];
    const float* bs1   = (const float*)d_in[8];
    const float* Ws2   = (const float*)d_in[9];
    const float* bs2   = (const float*)d_in[10];
    const float* Wm1   = (const float*)d_in[11];
    const float* bm1   = (const float*)d_in[12];
    const float* Wm2   = (const float*)d_in[13];
    const float* bm2   = (const float*)d_in[14];
    const float* Wout  = (const float*)d_in[15];
    const float* bout  = (const float*)d_in[16];
    float* out = (float*)d_out;

    float* ws     = (float*)d_ws;
    float* state  = ws;                              // 3,178,496 f32
    float* Ws14   = ws + 3178496;                    // 65,536
    float* logits = ws + 3244032;                    // 2*64*96 = 12,288 (ping-pong)
    int*   acts   = (int*)(ws + 3256320);            // 12,288 ints (ping-pong)
    int*   rec    = (int*)(ws + 3268608);            // 512 ints (ping-pong)
    int*   nlUsed = (int*)(ws + 3269120);            // 64 ints
    float* Psel   = ws + 3269184;                    // 2*64*16*256 = 524,288 (ping-pong)
    float* x1g    = ws + 3269184;                    // alias: Psel dead after scan
    float* x2g    = ws + 3334720;                    // alias

    k_trans_sel<<<dim3(128), dim3(128), 0, stream>>>(Wsel1, Ws14);
    k_init<<<dim3(NB), dim3(SS), 0, stream>>>(acts, rec);
    k_encode<<<dim3(NB * 3), dim3(256), 0, stream>>>(sent, emb, Wenc, benc, state);
    k_logits0<<<dim3(NB * 5), dim3(128), 0, stream>>>(state, Ws14, bs1, Ws2, bs2, logits);

    for (int t = 0; t < SS - 1; t++)   // t = 0..94
        k_step<<<dim3(256), dim3(320), 0, stream>>>(Wcomp, bcomp, Ws14, bs1, Ws2, bs2,
                                                    logits, acts, rec, nlUsed, Psel, state, t);

    k_mlp1<<<dim3(NB * 4), dim3(256), 0, stream>>>(state, nlUsed, Wm1, bm1, x1g);
    k_mlp2<<<dim3(NB * 8), dim3(128), 0, stream>>>(x1g, Wm2, bm2, x2g);
    k_mlp3<<<dim3(NB), dim3(256), 0, stream>>>(x2g, Wout, bout, out);
}